// Round 12
// baseline (102.022 us; speedup 1.0000x reference)
//
#include <hip/hip_runtime.h>
#include <hip/hip_bf16.h>
#include <math.h>

// GAT layer B=8, N=2048, F=64 on gfx950.
// Round 12: k_attn K-loop rebuilt AITER-style: global_load_lds staging
// (zero VGPR -> allocator can't serialize it) + explicit s_waitcnt vmcnt(2)
// pacing (never 0), NO barriers in the loop (each wave self-stages its own
// chunks into a private 3-slot LDS ring; overwrite distance = 2 iterations).
// Consumption via 12-cyc ds_read_b128. P-gen/packed-e2/32x32 MFMA/XCD-pin
// carried from R10/R11. R7's glds failed via per-tile __syncthreads vmcnt(0)
// drains; this has none.

#define NN 2048
#define BB 8

typedef __attribute__((ext_vector_type(8))) short s8v;     // 8 bf16
typedef __attribute__((ext_vector_type(4))) float f4v;
typedef __attribute__((ext_vector_type(16))) float f16v;   // 32x32 acc
typedef __attribute__((ext_vector_type(4))) unsigned u4v;
typedef __attribute__((ext_vector_type(2))) unsigned long long u64v2;

static __device__ __forceinline__ unsigned pk_bf16(float lo, float hi) {
  __hip_bfloat162 t = __float22bfloat162_rn(float2{lo, hi});
  return *(unsigned*)&t;
}
static __device__ __forceinline__ unsigned short bf16rne(float x) {
  union { float f; unsigned u; } c; c.f = x;
  unsigned r = c.u + 0x7FFFu + ((c.u >> 16) & 1u);
  return (unsigned short)(r >> 16);
}
static __device__ __forceinline__ void glds16(const unsigned short* g,
                                              unsigned short* l) {
  __builtin_amdgcn_global_load_lds(
      (const __attribute__((address_space(1))) unsigned int*)g,
      (__attribute__((address_space(3))) unsigned int*)l, 16, 0, 0);
}

// ---------------- Kernel 1: Wh/e-factors (blocks 0..511) + adj masks (512..1535) ----------------
// (unchanged from R10/R11 — verified)
__global__ __launch_bounds__(256, 2) void k_pre(
    const float* __restrict__ adj, const float* __restrict__ h,
    const float* __restrict__ W, const float* __restrict__ a,
    unsigned long long* __restrict__ adjq, unsigned short* __restrict__ whswz,
    float2* __restrict__ e1pn, unsigned* __restrict__ e2pk) {
  const int t = threadIdx.x, lane = t & 63, w = t >> 6;

  if (blockIdx.x >= 512) {
    const int bid = blockIdx.x - 512;
    const int row = bid * 2 + (w >> 1);
    const int half = w & 1;
    const float* ar = adj + (size_t)row * NN + half * 1024;
    unsigned long long* aq = adjq + row * 32 + half * 16;
    #pragma unroll
    for (int it = 0; it < 16; ++it) {
      unsigned long long m = __ballot(ar[it * 64 + lane] > 0.f);
      if (lane == 0) aq[it] = m;
    }
    return;
  }

  __shared__ __align__(16) float hs[32][68];
  const int rowBase = blockIdx.x * 32;
  const int b = rowBase >> 11, n0 = rowBase & (NN - 1);

  float wr[64];
  #pragma unroll
  for (int k = 0; k < 16; ++k)
    *(f4v*)&wr[k * 4] = *(const f4v*)&W[lane * 64 + k * 4];

  #pragma unroll
  for (int qq = 0; qq < 2; ++qq) {
    const int idx = t + 256 * qq;
    const int r = idx >> 4, c = (idx & 15) * 4;
    *(f4v*)&hs[r][c] = *(const f4v*)&h[(size_t)(rowBase + r) * 64 + c];
  }
  const float a1v = a[lane], a2v = a[64 + lane];
  __syncthreads();

  const int r0 = w * 8;
  float acc[8];
  #pragma unroll
  for (int rr = 0; rr < 8; ++rr) acc[rr] = 0.f;
  #pragma unroll
  for (int f4i = 0; f4i < 16; ++f4i) {
    f4v hv[8];
    #pragma unroll
    for (int rr = 0; rr < 8; ++rr)
      hv[rr] = *(const f4v*)&hs[r0 + rr][f4i * 4];
    #pragma unroll
    for (int x = 0; x < 4; ++x) {
      const float wv = wr[f4i * 4 + x];
      #pragma unroll
      for (int rr = 0; rr < 8; ++rr) acc[rr] = fmaf(hv[rr][x], wv, acc[rr]);
    }
  }

  {  // 32x32 B-frag swizzle store: [b][jc][oh][lane'][8]
    union { s8v v; unsigned u[4]; } cv;
    cv.u[0] = pk_bf16(acc[0], acc[1]);
    cv.u[1] = pk_bf16(acc[2], acc[3]);
    cv.u[2] = pk_bf16(acc[4], acc[5]);
    cv.u[3] = pk_bf16(acc[6], acc[7]);
    const int jc = (n0 + w * 8) >> 4;
    const int oh = lane >> 5;
    const int lp = ((w & 1) << 5) + (lane & 31);
    unsigned short* dst = whswz + ((size_t)b << 17) + (jc << 10) + (oh << 9) + (lp << 3);
    *(s8v*)dst = cv.v;
  }

  float s1[8], s2[8];
  #pragma unroll
  for (int rr = 0; rr < 8; ++rr) { s1[rr] = acc[rr] * a1v; s2[rr] = acc[rr] * a2v; }
  #pragma unroll
  for (int m = 1; m < 64; m <<= 1)
    #pragma unroll
    for (int rr = 0; rr < 8; ++rr) {
      s1[rr] += __shfl_xor(s1[rr], m);
      s2[rr] += __shfl_xor(s2[rr], m);
    }
  #pragma unroll
  for (int rr = 0; rr < 8; ++rr) {
    if (lane == 0) {
      e1pn[rowBase + rr + r0] = float2{__expf(s1[rr]), __expf(0.2f * s1[rr])};
      e2pk[rowBase + rr + r0] =
          (unsigned)bf16rne(__expf(s2[rr])) |
          ((unsigned)bf16rne(__expf(0.2f * s2[rr])) << 16);
    }
  }
}

// ---------------- Kernel 2: fused attention, glds ring + vmcnt pacing ----------------
// 512 blocks x 256 thr (4 waves, 2 blocks/CU). b=g&7 (XCD-pinned), 32 i-rows.
// Wave w = j-quarter: 32 chunks of 16 j. Each wave self-stages chunk s into
// private LDS ring slot s%3 via 2 glds; consumes with vmcnt(2) pacing.
__global__ __launch_bounds__(256, 2) void k_attn(
    const unsigned long long* __restrict__ adjq,
    const unsigned short* __restrict__ whswz,
    const float2* __restrict__ e1png, const unsigned* __restrict__ e2pkg,
    float* __restrict__ out) {
  union SM {
    unsigned short sbuf[3][4][1024];   // 24 KB: [slot][wave][2KB chunk]
    float pc[4][32][68];               // 34.8 KB partial C (after loop)
  };
  __shared__ __align__(16) SM sm;
  __shared__ __align__(16) unsigned e2bf[NN];   // 8 KB packed {E2p,E2n}
  __shared__ float ls[4][32];

  const int t = threadIdx.x, lane = t & 63, w = t >> 6;
  const int m32 = lane & 31, kh = lane >> 5;
  const int g = blockIdx.x;
  const int b = g & 7;
  const int i0 = (g >> 3) << 5;
  const size_t bN = (size_t)b * NN;

  // stage packed e2 factors (2048 dwords)
  ((u4v*)e2bf)[t] = ((const u4v*)(e2pkg + bN))[t];
  ((u4v*)e2bf)[t + 256] = ((const u4v*)(e2pkg + bN))[t + 256];

  const float2 e1f = e1png[bN + i0 + m32];
  const float E1p = e1f.x, E1n = e1f.y;

  const unsigned long long* arow = adjq + (size_t)(i0 + m32) * 32 + w * 8;
  unsigned long long am[8];
  #pragma unroll
  for (int qq = 0; qq < 4; ++qq)
    *(u64v2*)&am[qq * 2] = *(const u64v2*)(arow + qq * 2);

  // this wave's chunk base: jc = w*32 + s
  const unsigned short* wbase = whswz + ((size_t)b << 17) + ((size_t)(w * 32) << 10);

  f16v acc0, acc1;
  #pragma unroll
  for (int r = 0; r < 16; ++r) { acc0[r] = 0.f; acc1[r] = 0.f; }
  float psA = 0.f, psB = 0.f;

  // prologue: issue steps 0,1 (2 glds each)
  #pragma unroll
  for (int s = 0; s < 2; ++s) {
    const unsigned short* gp = wbase + (s << 10) + (lane << 3);
    glds16(gp, &sm.sbuf[s][w][0]);
    glds16(gp + 512, &sm.sbuf[s][w][512]);
  }

  __syncthreads();   // e2bf visible (also drains prologue glds — once, ok)

  #pragma unroll
  for (int s = 0; s < 32; ++s) {
    // wait: chunk s landed; chunk s+1 may stay in flight
    if (s < 31) __builtin_amdgcn_s_waitcnt(0x0F72);   // vmcnt(2)
    else        __builtin_amdgcn_s_waitcnt(0x0F70);   // vmcnt(0)
    __asm__ volatile("" ::: "memory");                // pin ds_reads below wait

    const int r = s % 3;
    const s8v bf0 = *(const s8v*)&sm.sbuf[r][w][lane << 3];
    const s8v bf1 = *(const s8v*)&sm.sbuf[r][w][512 + (lane << 3)];

    // ---- P-gen (LDS e2bf + registers) ----
    const int eb = ((w * 32 + s) << 4) + (kh << 3);
    const u4v e0 = *(const u4v*)&e2bf[eb];
    const u4v e1 = *(const u4v*)&e2bf[eb + 4];
    const unsigned bits = (unsigned)(am[s >> 2] >> ((s & 3) * 16 + kh * 8)) & 0xffu;
    float p[8];
    #pragma unroll
    for (int e = 0; e < 8; ++e) {
      const unsigned dw = e < 4 ? e0[e] : e1[e - 4];
      const float E2p = __uint_as_float(dw << 16);
      const float E2n = __uint_as_float(dw & 0xffff0000u);
      const float mp = E1p * E2p;                // exp(e1+e2)
      const float mn = E1n * E2n;                // exp(0.2*(e1+e2))
      float pv = mp > 1.f ? mp : mn;             // leaky-relu in exp domain
      pv = ((bits >> e) & 1u) ? pv : 0.f;
      p[e] = pv;
    }
    {
      const float s01 = p[0] + p[1], s23 = p[2] + p[3];
      const float s45 = p[4] + p[5], s67 = p[6] + p[7];
      if (s & 1) psB += (s01 + s23) + (s45 + s67);
      else       psA += (s01 + s23) + (s45 + s67);
    }
    s8v af;
    {
      union { s8v v; unsigned u[4]; } cv;
      cv.u[0] = pk_bf16(p[0], p[1]);
      cv.u[1] = pk_bf16(p[2], p[3]);
      cv.u[2] = pk_bf16(p[4], p[5]);
      cv.u[3] = pk_bf16(p[6], p[7]);
      af = cv.v;
    }

    acc0 = __builtin_amdgcn_mfma_f32_32x32x16_bf16(af, bf0, acc0, 0, 0, 0);
    acc1 = __builtin_amdgcn_mfma_f32_32x32x16_bf16(af, bf1, acc1, 0, 0, 0);

    // refill slot (s+2)%3 — 2 iterations away from its last reader
    __asm__ volatile("" ::: "memory");                // pin glds after ds_reads
    if (s + 2 < 32) {
      const int rn = (s + 2) % 3;
      const unsigned short* gp = wbase + ((s + 2) << 10) + (lane << 3);
      glds16(gp, &sm.sbuf[rn][w][0]);
      glds16(gp + 512, &sm.sbuf[rn][w][512]);
    }
  }

  // rowsum merge across k-halves
  float psum = psA + psB;
  psum += __shfl_xor(psum, 32);
  __syncthreads();              // all sbuf reads done -> pc alias safe
  if (lane < 32) ls[w][lane] = psum;
  // publish partial C (C/D 32x32 layout: col=lane&31, row=(r&3)+8*(r>>2)+4*kh)
  #pragma unroll
  for (int r = 0; r < 16; ++r) {
    const int row = (r & 3) + 8 * (r >> 2) + 4 * kh;
    sm.pc[w][row][m32] = acc0[r];
    sm.pc[w][row][32 + m32] = acc1[r];
  }
  __syncthreads();

  // gather across 4 waves: thread t -> row t>>3, 8 cols at (t&7)*8
  const int row = t >> 3, c0 = (t & 7) * 8;
  f4v s0 = *(const f4v*)&sm.pc[0][row][c0];
  f4v s1 = *(const f4v*)&sm.pc[0][row][c0 + 4];
  #pragma unroll
  for (int j = 1; j < 4; ++j) {
    s0 += *(const f4v*)&sm.pc[j][row][c0];
    s1 += *(const f4v*)&sm.pc[j][row][c0 + 4];
  }
  const float rsum = ls[0][row] + ls[1][row] + ls[2][row] + ls[3][row];
  f4v o0, o1;
  #pragma unroll
  for (int xx = 0; xx < 4; ++xx) {
    float v = s0[xx] / rsum;
    o0[xx] = v > 0.f ? v : expm1f(v);
    v = s1[xx] / rsum;
    o1[xx] = v > 0.f ? v : expm1f(v);
  }
  float* op = &out[(bN + i0 + row) * 64 + c0];
  *(f4v*)op = o0;
  *(f4v*)(op + 4) = o1;
}

extern "C" void kernel_launch(void* const* d_in, const int* in_sizes, int n_in,
                              void* d_out, int out_size, void* d_ws, size_t ws_size,
                              hipStream_t stream) {
  (void)in_sizes; (void)n_in; (void)out_size; (void)ws_size;
  const float* h   = (const float*)d_in[0];
  const float* adj = (const float*)d_in[1];
  const float* W   = (const float*)d_in[2];
  const float* a   = (const float*)d_in[3];
  float* outp = (float*)d_out;

  // ws carve: whswz 2 MB | e1pn 128 KB | e2pk 64 KB | adjq 512 KB
  unsigned short* whswz = (unsigned short*)d_ws;
  float2* e1pn = (float2*)((char*)d_ws + (size_t)BB * 64 * NN * 2);
  unsigned* e2pk = (unsigned*)(e1pn + (size_t)BB * NN);
  unsigned long long* adjq = (unsigned long long*)(e2pk + (size_t)BB * NN);

  k_pre<<<1536, 256, 0, stream>>>(adj, h, W, a, adjq, whswz, e1pn, e2pk);
  k_attn<<<512, 256, 0, stream>>>(adjq, whswz, e1pn, e2pk, outp);
}

// Round 13
// 94.641 us; speedup vs baseline: 1.0780x; 1.0780x over previous
//
#include <hip/hip_runtime.h>
#include <hip/hip_bf16.h>
#include <math.h>

// GAT layer B=8, N=2048, F=64 on gfx950.
// Round 13: k_attn = R10 verbatim (best measured: 97.9us total).
// k_pre fix: W staged through LDS coalesced (was lane-divergent 64-line
// dwordx4 loads: 1024 line-transactions/wave at every wave's head), then
// wr[64] filled via conflict-free ds_read_b128 (65-pad: (lane+4k)&31).

#define NN 2048
#define BB 8

typedef __attribute__((ext_vector_type(8))) short s8v;     // 8 bf16
typedef __attribute__((ext_vector_type(4))) float f4v;
typedef __attribute__((ext_vector_type(16))) float f16v;   // 32x32 acc
typedef __attribute__((ext_vector_type(4))) unsigned u4v;

static __device__ __forceinline__ unsigned pk_bf16(float lo, float hi) {
  __hip_bfloat162 t = __float22bfloat162_rn(float2{lo, hi});
  return *(unsigned*)&t;
}
static __device__ __forceinline__ unsigned short bf16rne(float x) {
  union { float f; unsigned u; } c; c.f = x;
  unsigned r = c.u + 0x7FFFu + ((c.u >> 16) & 1u);
  return (unsigned short)(r >> 16);
}

// ---------------- Kernel 1: Wh/e-factors (blocks 0..511) + adj masks (512..1535) ----------------
__global__ __launch_bounds__(256, 2) void k_pre(
    const float* __restrict__ adj, const float* __restrict__ h,
    const float* __restrict__ W, const float* __restrict__ a,
    unsigned long long* __restrict__ adjq, unsigned short* __restrict__ whswz,
    float2* __restrict__ e1pn, unsigned* __restrict__ e2pk) {
  const int t = threadIdx.x, lane = t & 63, w = t >> 6;

  if (blockIdx.x >= 512) {
    // ---- adj -> bit rows: 2 rows/block, wave -> half row, 16 ballots ----
    const int bid = blockIdx.x - 512;
    const int row = bid * 2 + (w >> 1);
    const int half = w & 1;
    const float* ar = adj + (size_t)row * NN + half * 1024;
    unsigned long long* aq = adjq + row * 32 + half * 16;
    #pragma unroll
    for (int it = 0; it < 16; ++it) {
      unsigned long long m = __ballot(ar[it * 64 + lane] > 0.f);
      if (lane == 0) aq[it] = m;
    }
    return;
  }

  // ---- Wh (bf16, 32x32-B-frag swizzle) + e-factors; 32 n-rows/block ----
  __shared__ __align__(16) float hs[32][68];    //  8.7 KB
  __shared__ __align__(16) float Wl[64][65];    // 16.6 KB staged W
  const int rowBase = blockIdx.x * 32;
  const int b = rowBase >> 11, n0 = rowBase & (NN - 1);

  // coalesced W stage: 1024 float4s, 4 rounds
  #pragma unroll
  for (int qq = 0; qq < 4; ++qq) {
    const int idx = t + 256 * qq;                // f4v id 0..1023
    const int r = idx >> 4, c = (idx & 15) * 4;  // idx*4 == r*64+c
    *(f4v*)&Wl[r][c] = *(const f4v*)&W[idx * 4];
  }
  #pragma unroll
  for (int qq = 0; qq < 2; ++qq) {
    const int idx = t + 256 * qq;                // 512 float4s of h
    const int r = idx >> 4, c = (idx & 15) * 4;
    *(f4v*)&hs[r][c] = *(const f4v*)&h[(size_t)(rowBase + r) * 64 + c];
  }
  const float a1v = a[lane], a2v = a[64 + lane];
  __syncthreads();

  // wr[64] = W row `lane` via conflict-free ds_read_b128 (65-pad)
  float wr[64];
  #pragma unroll
  for (int k = 0; k < 16; ++k)
    *(f4v*)&wr[k * 4] = *(const f4v*)&Wl[lane][k * 4];

  const int r0 = w * 8;                          // 8 n-rows per wave
  float acc[8];
  #pragma unroll
  for (int rr = 0; rr < 8; ++rr) acc[rr] = 0.f;
  #pragma unroll
  for (int f4i = 0; f4i < 16; ++f4i) {
    f4v hv[8];
    #pragma unroll
    for (int rr = 0; rr < 8; ++rr)
      hv[rr] = *(const f4v*)&hs[r0 + rr][f4i * 4];       // lane-uniform broadcast
    #pragma unroll
    for (int x = 0; x < 4; ++x) {
      const float wv = wr[f4i * 4 + x];
      #pragma unroll
      for (int rr = 0; rr < 8; ++rr) acc[rr] = fmaf(hv[rr][x], wv, acc[rr]);
    }
  }

  {  // 32x32 B-frag swizzle store: [b][jc][oh][lane'][8], 16B/thread
    union { s8v v; unsigned u[4]; } cv;
    cv.u[0] = pk_bf16(acc[0], acc[1]);
    cv.u[1] = pk_bf16(acc[2], acc[3]);
    cv.u[2] = pk_bf16(acc[4], acc[5]);
    cv.u[3] = pk_bf16(acc[6], acc[7]);
    const int jc = (n0 + w * 8) >> 4;            // 16-j chunk
    const int oh = lane >> 5;                    // o-half
    const int lp = ((w & 1) << 5) + (lane & 31); // lane' = ksub*32 + n
    unsigned short* dst = whswz + ((size_t)b << 17) + (jc << 10) + (oh << 9) + (lp << 3);
    *(s8v*)dst = cv.v;
  }

  float s1[8], s2[8];
  #pragma unroll
  for (int rr = 0; rr < 8; ++rr) { s1[rr] = acc[rr] * a1v; s2[rr] = acc[rr] * a2v; }
  #pragma unroll
  for (int m = 1; m < 64; m <<= 1)
    #pragma unroll
    for (int rr = 0; rr < 8; ++rr) {
      s1[rr] += __shfl_xor(s1[rr], m);
      s2[rr] += __shfl_xor(s2[rr], m);
    }
  #pragma unroll
  for (int rr = 0; rr < 8; ++rr) {
    if (lane == 0) {
      e1pn[rowBase + rr + r0] = float2{__expf(s1[rr]), __expf(0.2f * s1[rr])};
      e2pk[rowBase + rr + r0] =
          (unsigned)bf16rne(__expf(s2[rr])) |
          ((unsigned)bf16rne(__expf(0.2f * s2[rr])) << 16);
    }
  }
}

// ---------------- Kernel 2: fused attention, 32x32x16 MFMA (R10 verbatim) ----------------
// 512 blocks x 512 thr (8 waves). b = g&7 (XCD-pinned). Block = 32 i-rows.
// Wave w = j-eighth (16 chunks of 16 j). Thread owns A[m=lane&31][k=kh*8+e].
__global__ __launch_bounds__(512, 4) void k_attn(
    const unsigned long long* __restrict__ adjq,
    const unsigned short* __restrict__ whswz,
    const float2* __restrict__ e1png, const unsigned* __restrict__ e2pkg,
    float* __restrict__ out) {
  union SM {
    unsigned e2bf[NN];          //  8 KB packed {E2p,E2n} bf16 per j
    float pc[8][32][68];        // 69.6 KB partial C (aliased; used after loop)
  };
  __shared__ __align__(16) SM sm;
  __shared__ float ls[8][32];

  const int t = threadIdx.x, lane = t & 63, w = t >> 6;
  const int m32 = lane & 31, kh = lane >> 5;
  const int g = blockIdx.x;
  const int b = g & 7;                 // XCD g%8 <-> batch b
  const int i0 = (g >> 3) << 5;
  const size_t bN = (size_t)b * NN;

  // stage packed e2 factors: 512 x u4v = 2048 dwords
  ((u4v*)sm.e2bf)[t] = ((const u4v*)(e2pkg + bN))[t];

  const float2 e1f = e1png[bN + i0 + m32];
  const float E1p = e1f.x, E1n = e1f.y;
  const unsigned long long* arow = adjq + (size_t)(i0 + m32) * 32 + w * 4;
  const unsigned short* wb = whswz + ((size_t)b << 17);

  f16v acc0, acc1;
  #pragma unroll
  for (int r = 0; r < 16; ++r) { acc0[r] = 0.f; acc1[r] = 0.f; }
  float psum = 0.f;

  auto pgen = [&](u4v e0, u4v e1, unsigned bits) -> s8v {
    float p[8];
    #pragma unroll
    for (int e = 0; e < 8; ++e) {
      const unsigned dw = e < 4 ? e0[e] : e1[e - 4];
      const float E2p = __uint_as_float(dw << 16);
      const float E2n = __uint_as_float(dw & 0xffff0000u);
      const float mp = E1p * E2p;          // exp(e1+e2)
      const float mn = E1n * E2n;          // exp(0.2*(e1+e2))
      float pv = mp > 1.f ? mp : mn;       // leaky-relu in exp domain
      pv = ((bits >> e) & 1u) ? pv : 0.f;
      psum += pv;
      p[e] = pv;
    }
    union { s8v v; unsigned u[4]; } cv;
    cv.u[0] = pk_bf16(p[0], p[1]);
    cv.u[1] = pk_bf16(p[2], p[3]);
    cv.u[2] = pk_bf16(p[4], p[5]);
    cv.u[3] = pk_bf16(p[6], p[7]);
    return cv.v;
  };

  __syncthreads();   // e2bf staged

  unsigned long long am = 0;
  #pragma unroll
  for (int it = 0; it < 8; ++it) {
    const int jcl = it * 2;                       // local chunk 0..15
    const int jcA = w * 16 + jcl, jcB = jcA + 1;
    // B-fragments: 4 coalesced 1KB loads
    const s8v bA0 = *(const s8v*)(wb + (jcA << 10) + (lane << 3));
    const s8v bA1 = *(const s8v*)(wb + (jcA << 10) + 512 + (lane << 3));
    const s8v bB0 = *(const s8v*)(wb + (jcB << 10) + (lane << 3));
    const s8v bB1 = *(const s8v*)(wb + (jcB << 10) + 512 + (lane << 3));
    if ((it & 1) == 0) am = arow[it >> 1];        // one 64-j word per 2 iters
    // e2 factor reads (broadcast, 2 distinct addrs/wave)
    const u4v eA0 = *(const u4v*)&sm.e2bf[(jcA << 4) + (kh << 3)];
    const u4v eA1 = *(const u4v*)&sm.e2bf[(jcA << 4) + (kh << 3) + 4];
    const u4v eB0 = *(const u4v*)&sm.e2bf[(jcB << 4) + (kh << 3)];
    const u4v eB1 = *(const u4v*)&sm.e2bf[(jcB << 4) + (kh << 3) + 4];

    const unsigned bitsA = (unsigned)(am >> (((jcl)&3) * 16 + kh * 8)) & 0xffu;
    const unsigned bitsB = (unsigned)(am >> (((jcl + 1) & 3) * 16 + kh * 8)) & 0xffu;
    const s8v afA = pgen(eA0, eA1, bitsA);
    const s8v afB = pgen(eB0, eB1, bitsB);

    acc0 = __builtin_amdgcn_mfma_f32_32x32x16_bf16(afA, bA0, acc0, 0, 0, 0);
    acc1 = __builtin_amdgcn_mfma_f32_32x32x16_bf16(afA, bA1, acc1, 0, 0, 0);
    acc0 = __builtin_amdgcn_mfma_f32_32x32x16_bf16(afB, bB0, acc0, 0, 0, 0);
    acc1 = __builtin_amdgcn_mfma_f32_32x32x16_bf16(afB, bB1, acc1, 0, 0, 0);
  }

  // rowsum: thread's 8 P's/chunk all belong to row m32; merge k-halves
  psum += __shfl_xor(psum, 32);
  __syncthreads();              // all e2bf reads done -> pc alias safe
  if (lane < 32) ls[w][lane] = psum;
  // publish partial C (C/D layout m74/m101: col=lane&31, row=(r&3)+8*(r>>2)+4*kh)
  #pragma unroll
  for (int r = 0; r < 16; ++r) {
    const int row = (r & 3) + 8 * (r >> 2) + 4 * kh;
    sm.pc[w][row][m32] = acc0[r];
    sm.pc[w][row][32 + m32] = acc1[r];
  }
  __syncthreads();

  // gather across 8 waves: thread t -> row t>>4, cols (t&15)*4
  const int row = t >> 4, c0 = (t & 15) * 4;
  f4v sum = *(const f4v*)&sm.pc[0][row][c0];
  #pragma unroll
  for (int j = 1; j < 8; ++j) sum += *(const f4v*)&sm.pc[j][row][c0];
  float rsum = ls[0][row];
  #pragma unroll
  for (int j = 1; j < 8; ++j) rsum += ls[j][row];
  f4v o;
  #pragma unroll
  for (int x = 0; x < 4; ++x) {
    float v = sum[x] / rsum;
    o[x] = v > 0.f ? v : expm1f(v);
  }
  *(f4v*)&out[(bN + i0 + row) * 64 + c0] = o;
}

extern "C" void kernel_launch(void* const* d_in, const int* in_sizes, int n_in,
                              void* d_out, int out_size, void* d_ws, size_t ws_size,
                              hipStream_t stream) {
  (void)in_sizes; (void)n_in; (void)out_size; (void)ws_size;
  const float* h   = (const float*)d_in[0];
  const float* adj = (const float*)d_in[1];
  const float* W   = (const float*)d_in[2];
  const float* a   = (const float*)d_in[3];
  float* outp = (float*)d_out;

  // ws carve: whswz 2 MB | e1pn 128 KB | e2pk 64 KB | adjq 512 KB
  unsigned short* whswz = (unsigned short*)d_ws;
  float2* e1pn = (float2*)((char*)d_ws + (size_t)BB * 64 * NN * 2);
  unsigned* e2pk = (unsigned*)(e1pn + (size_t)BB * NN);
  unsigned long long* adjq = (unsigned long long*)(e2pk + (size_t)BB * NN);

  k_pre<<<1536, 256, 0, stream>>>(adj, h, W, a, adjq, whswz, e1pn, e2pk);
  k_attn<<<512, 512, 0, stream>>>(adjq, whswz, e1pn, e2pk, outp);
}